// Round 6
// baseline (498.826 us; speedup 1.0000x reference)
//
#include <hip/hip_runtime.h>
#include <math.h>

// B=4, C=256, N=H*W=4096, G=32. All inputs/output FLOAT32; bf16 internally.
// out = x + nin3( attn( nin0/1/2( groupnorm(x) ) ) )
//
// Fixed-M flash attention (exp2-domain bound M2=24): partials additive across
// key-splits; ks = 4 if ws_size permits (partials 0,1 in d_out; 2,3 in ws),
// else ks = 2 (partials fit d_out exactly).

typedef short short8    __attribute__((ext_vector_type(8)));
typedef ushort ushort8  __attribute__((ext_vector_type(8)));
typedef float f32x4     __attribute__((ext_vector_type(4)));

#define BB 4
#define CCH 256
#define NSP 4096
#define TEN ((size_t)BB * NSP * CCH)

__device__ __forceinline__ float b2f(ushort h){
  unsigned int u = ((unsigned int)h) << 16;
  float f; __builtin_memcpy(&f, &u, 4); return f;
}
__device__ __forceinline__ ushort f2b(float f){
  unsigned int u; __builtin_memcpy(&u, &f, 4);
  u += 0x7fffu + ((u >> 16) & 1u);   // RTNE
  return (ushort)(u >> 16);
}

// ---------------- GroupNorm stats ----------------
__global__ __launch_bounds__(256) void gn_stats_k(const float* __restrict__ x,
                                                  float* __restrict__ stats){
  const int bg = blockIdx.x;
  const f32x4* p = (const f32x4*)(x + (size_t)bg * 32768);
  float s = 0.f, s2 = 0.f;
  for (int i = threadIdx.x; i < 8192; i += 256){
    f32x4 v = p[i];
    #pragma unroll
    for (int j = 0; j < 4; j++){ s += v[j]; s2 += v[j]*v[j]; }
  }
  #pragma unroll
  for (int off = 32; off >= 1; off >>= 1){
    s  += __shfl_down(s,  off, 64);
    s2 += __shfl_down(s2, off, 64);
  }
  __shared__ float red[8];
  const int w = threadIdx.x >> 6;
  if ((threadIdx.x & 63) == 0){ red[w*2] = s; red[w*2+1] = s2; }
  __syncthreads();
  if (threadIdx.x == 0){
    float S  = red[0]+red[2]+red[4]+red[6];
    float S2 = red[1]+red[3]+red[5]+red[7];
    float mean = S * (1.f/32768.f);
    float var  = fmaxf(S2 * (1.f/32768.f) - mean*mean, 0.f);
    stats[bg*2]   = mean;
    stats[bg*2+1] = rsqrtf(var + 1e-6f);
  }
}

// ------- GN apply + transpose + cast: x[b][c][n] f32 -> h_t[b][n][c] bf16 ------
__global__ __launch_bounds__(256) void gn_apply_k(const float* __restrict__ x,
                                                  const float* __restrict__ stats,
                                                  const float* __restrict__ gamma,
                                                  const float* __restrict__ beta,
                                                  ushort* __restrict__ h_t){
  __shared__ ushort tile[64][72];
  const int b = blockIdx.z, c0 = blockIdx.y*64, n0 = blockIdx.x*64;
  const int t = threadIdx.x;
  #pragma unroll
  for (int p = 0; p < 2; p++){
    const int cl = p*32 + (t >> 3);
    const int nc = (t & 7) * 8;
    const int c = c0 + cl;
    const float mean = stats[(b*32 + (c>>3))*2];
    const float rstd = stats[(b*32 + (c>>3))*2 + 1];
    const float sc = rstd * gamma[c];
    const float sh = beta[c] - mean * sc;
    const float* xr = x + ((size_t)b*CCH + c)*NSP + n0 + nc;
    f32x4 a = *(const f32x4*)xr;
    f32x4 d = *(const f32x4*)(xr + 4);
    #pragma unroll
    for (int j = 0; j < 4; j++){
      tile[nc + j][cl]     = f2b(a[j]*sc + sh);
      tile[nc + 4 + j][cl] = f2b(d[j]*sc + sh);
    }
  }
  __syncthreads();
  #pragma unroll
  for (int p = 0; p < 2; p++){
    const int nl = p*32 + (t >> 3);
    const int cc = (t & 7) * 8;
    ushort8 ov;
    #pragma unroll
    for (int j = 0; j < 8; j++) ov[j] = tile[nl][cc + j];
    *(ushort8*)(h_t + ((size_t)b*NSP + n0 + nl)*CCH + c0 + cc) = ov;
  }
}

// ------- weight transpose + cast ------------------------------------------------
__global__ __launch_bounds__(256) void transpose_w4_k(const float* __restrict__ w0,
                                                      const float* __restrict__ w1,
                                                      const float* __restrict__ w2,
                                                      const float* __restrict__ w3,
                                                      ushort* __restrict__ wT){
  __shared__ ushort tile[64][72];
  const float* w = (blockIdx.y==0) ? w0 : (blockIdx.y==1) ? w1 : (blockIdx.y==2) ? w2 : w3;
  ushort* dst = wT + (size_t)blockIdx.y * 65536;
  const int tb = blockIdx.x;
  const int r0 = (tb >> 2) * 64, c0 = (tb & 3) * 64;
  const int t = threadIdx.x;
  #pragma unroll
  for (int p = 0; p < 2; p++){
    const int r = p*32 + (t >> 3), cc = (t & 7)*8;
    const float* wr = w + (size_t)(r0 + r)*256 + c0 + cc;
    f32x4 a = *(const f32x4*)wr;
    f32x4 d = *(const f32x4*)(wr + 4);
    #pragma unroll
    for (int j = 0; j < 4; j++){
      tile[r][cc + j]     = f2b(a[j]);
      tile[r][cc + 4 + j] = f2b(d[j]);
    }
  }
  __syncthreads();
  #pragma unroll
  for (int p = 0; p < 2; p++){
    const int r = p*32 + (t >> 3), cc = (t & 7)*8;
    ushort8 ov;
    #pragma unroll
    for (int j = 0; j < 8; j++) ov[j] = tile[cc + j][r];
    *(ushort8*)(dst + (size_t)(c0 + r)*256 + r0 + cc) = ov;
  }
}

// ------------- GEMM with LDS-staged B-tile (swizzled) --------------------------
// D[m][n] = sum_k A[m][k]*B[n][k]; OutT[n][m] bf16. K = 256.
__global__ __launch_bounds__(256) void gemm_lds_k(const ushort* __restrict__ A,
                                                  const ushort* __restrict__ B,
                                                  ushort* __restrict__ OutT,
                                                  int M, int N,
                                                  long aStride, long bStride, long oStride,
                                                  const float* __restrict__ biasM,
                                                  const float* __restrict__ biasN){
  __shared__ ushort Bt[64*256];            // 32 KB, granule-swizzled
  const int K = 256;
  const int t = threadIdx.x, w = t >> 6, lane = t & 63;
  const int li = lane & 15, quad = lane >> 4;
  const int m64 = M >> 6;
  const int tm = blockIdx.x % m64, tn = blockIdx.x / m64;
  const int batch = blockIdx.y;
  A    += (size_t)batch * aStride;
  B    += (size_t)batch * bStride;
  OutT += (size_t)batch * oStride;
  const int m0 = tm*64 + w*16;
  const int nb = tn*64;

  #pragma unroll
  for (int i = 0; i < 8; i++){
    const int id = t + 256*i;
    const int row = id >> 5, gg = id & 31;
    *(ushort8*)&Bt[row*256 + (gg ^ (row & 31))*8] =
      *(const ushort8*)(B + (size_t)(nb + row)*K + gg*8);
  }
  short8 afr[8];
  #pragma unroll
  for (int kk = 0; kk < 8; kk++)
    afr[kk] = *(const short8*)(A + (size_t)(m0 + li)*K + kk*32 + quad*8);
  __syncthreads();

  #pragma unroll
  for (int nt = 0; nt < 4; nt++){
    f32x4 acc = {0.f,0.f,0.f,0.f};
    const int n = nb + nt*16 + li;
    const int rowl = nt*16 + li;
    #pragma unroll
    for (int kk = 0; kk < 8; kk++){
      short8 bfr = *(const short8*)&Bt[rowl*256 + ((4*kk + quad) ^ (rowl & 31))*8];
      acc = __builtin_amdgcn_mfma_f32_16x16x32_bf16(afr[kk], bfr, acc, 0, 0, 0);
    }
    const float bn = biasN ? biasN[n] : 0.f;
    ushort ov[4];
    #pragma unroll
    for (int r = 0; r < 4; r++){
      const float bm = biasM ? biasM[m0 + quad*4 + r] : 0.f;
      ov[r] = f2b(acc[r] + bm + bn);
    }
    *(uint2*)(OutT + (size_t)n*M + m0 + quad*4) = *(uint2*)ov;
  }
}

// ---------------- fixed-M flash attention, runtime key-split -------------------
// grid BB*64*ks: bx -> qt = bx&63, b = (bx>>6)&3, s = bx>>8. 4 waves x 16 q.
__global__ __launch_bounds__(256, 3) void attn_k(const ushort* __restrict__ qg,
                                                 const ushort* __restrict__ kg,
                                                 const ushort* __restrict__ vg,
                                                 ushort* __restrict__ ph01,
                                                 ushort* __restrict__ ph23,
                                                 float* __restrict__ lbuf,
                                                 int iters){
  __shared__ ushort KtS[32*256];           // 16 KB, swizzled [key][c]
  __shared__ ushort VtS[256*40];           // 20 KB, [c][key] stride 40
  __shared__ ushort Pl[4][16][40];         //  5 KB per-wave P

  const int t = threadIdx.x, w = t >> 6, lane = t & 63;
  const int li = lane & 15, quad = lane >> 4;
  const int bx = blockIdx.x;
  const int qt = bx & 63, b = (bx >> 6) & 3, s = bx >> 8;
  const int n0 = qt * 64;
  const int keybase = s * (iters * 32);

  const ushort* kb = kg + (size_t)b*NSP*CCH;
  const ushort* vb = vg + (size_t)b*CCH*NSP;

  short8 qf[8];
  {
    const ushort* qrow = qg + ((size_t)b*NSP + n0 + w*16 + li)*CCH + quad*8;
    #pragma unroll
    for (int kk = 0; kk < 8; kk++) qf[kk] = *(const short8*)(qrow + kk*32);
  }

  f32x4 oacc[16];
  #pragma unroll
  for (int i = 0; i < 16; i++) oacc[i] = (f32x4){0.f,0.f,0.f,0.f};
  float l_i[4] = {0.f,0.f,0.f,0.f};
  const float c1 = 0.0625f * 1.44269504088896f;  // C^-0.5 * log2(e)
  const float M2 = 24.f;                         // fixed exp2-domain max bound

  ushort8 kreg[4], vreg[4];
  #pragma unroll
  for (int i = 0; i < 4; i++){                   // prologue loads (tile 0)
    const int id = t + 256*i;
    kreg[i] = *(const ushort8*)(kb + (size_t)(keybase + (id>>5))*CCH + (id&31)*8);
    vreg[i] = *(const ushort8*)(vb + (size_t)(id>>2)*NSP + keybase + (id&3)*8);
  }

  for (int it = 0; it < iters; it++){
    __syncthreads();                             // previous tile's reads done
    #pragma unroll
    for (int i = 0; i < 4; i++){
      const int id = t + 256*i;
      const int row = id >> 5, g = id & 31;
      *(ushort8*)&KtS[row*256 + (g ^ (row & 31))*8] = kreg[i];
      *(ushort8*)&VtS[(id>>2)*40 + (id&3)*8] = vreg[i];
    }
    __syncthreads();                             // staged
    if (it + 1 < iters){                         // prefetch next tile -> regs
      const int nk0 = keybase + (it+1)*32;
      #pragma unroll
      for (int i = 0; i < 4; i++){
        const int id = t + 256*i;
        kreg[i] = *(const ushort8*)(kb + (size_t)(nk0 + (id>>5))*CCH + (id&31)*8);
        vreg[i] = *(const ushort8*)(vb + (size_t)(id>>2)*NSP + nk0 + (id&3)*8);
      }
    }

    f32x4 sacc[2];
    #pragma unroll
    for (int nt = 0; nt < 2; nt++) sacc[nt] = (f32x4){0.f,0.f,0.f,0.f};
    #pragma unroll
    for (int nt = 0; nt < 2; nt++){
      const int row = nt*16 + li;
      #pragma unroll
      for (int kk = 0; kk < 8; kk++){
        short8 bfr = *(const short8*)&KtS[row*256 + ((4*kk + quad) ^ (row & 31))*8];
        sacc[nt] = __builtin_amdgcn_mfma_f32_16x16x32_bf16(qf[kk], bfr, sacc[nt], 0, 0, 0);
      }
    }

    // fixed-M softmax: P = exp2(s*c1 - M2); l accumulates per-lane (reduce at end)
    #pragma unroll
    for (int nt = 0; nt < 2; nt++){
      #pragma unroll
      for (int r = 0; r < 4; r++){
        const float pv = __builtin_amdgcn_exp2f(fminf(sacc[nt][r]*c1 - M2, 30.f));
        l_i[r] += pv;
        Pl[w][quad*4 + r][nt*16 + li] = f2b(pv);
      }
    }

    // O += P * V  (A-frag from per-wave Pl, B-frag from VtS)
    {
      short8 af = *(const short8*)&Pl[w][li][quad*8];
      #pragma unroll
      for (int ct = 0; ct < 16; ct++){
        short8 vf = *(const short8*)&VtS[(ct*16 + li)*40 + quad*8];
        oacc[ct] = __builtin_amdgcn_mfma_f32_16x16x32_bf16(af, vf, oacc[ct], 0, 0, 0);
      }
    }
  }

  // write partial O (un-normalized, bf16) + l
  ushort* ps = (s < 2) ? (ph01 + (size_t)s*TEN) : (ph23 + (size_t)(s-2)*TEN);
  const size_t base = ((size_t)b*NSP + n0 + w*16) * CCH;
  #pragma unroll
  for (int ct = 0; ct < 16; ct++){
    #pragma unroll
    for (int r = 0; r < 4; r++)
      ps[base + (size_t)(quad*4 + r)*CCH + ct*16 + li] = f2b(oacc[ct][r]);
  }
  #pragma unroll
  for (int off = 1; off < 16; off <<= 1){
    #pragma unroll
    for (int r = 0; r < 4; r++) l_i[r] += __shfl_xor(l_i[r], off, 64);
  }
  if (li == 0){
    #pragma unroll
    for (int r = 0; r < 4; r++)
      lbuf[(size_t)s*BB*NSP + (size_t)b*NSP + n0 + w*16 + quad*4 + r] = l_i[r];
  }
}

// ---------------- combine ks partials -> Oc bf16 -------------------------------
__global__ __launch_bounds__(256) void combine_k(const ushort* __restrict__ ph01,
                                                 const ushort* __restrict__ ph23,
                                                 const float* __restrict__ lbuf,
                                                 ushort* __restrict__ Oc, int ks){
  const size_t g = (size_t)blockIdx.x*256 + threadIdx.x;
  const size_t idx = g >> 5;                 // (b*4096+n), 16384 rows
  const int cb = (int)(g & 31) * 8;
  float suml = 0.f;
  for (int s = 0; s < ks; s++) suml += lbuf[(size_t)s*BB*NSP + idx];
  float acc[8] = {0,0,0,0,0,0,0,0};
  for (int s = 0; s < ks; s++){
    const ushort* ps = (s < 2) ? (ph01 + (size_t)s*TEN) : (ph23 + (size_t)(s-2)*TEN);
    ushort8 p = *(const ushort8*)(ps + idx*CCH + cb);
    #pragma unroll
    for (int j = 0; j < 8; j++) acc[j] += b2f(p[j]);
  }
  const float rl = 1.f / suml;
  ushort8 o;
  #pragma unroll
  for (int j = 0; j < 8; j++) o[j] = f2b(acc[j]*rl);
  *(ushort8*)(Oc + idx*CCH + cb) = o;
}

// ---------------- final projection + bias + residual (f32 out) -----------------
__global__ __launch_bounds__(256) void gemm_proj_k(const ushort* __restrict__ A,
                                                   const ushort* __restrict__ Bm,
                                                   const float* __restrict__ b3,
                                                   const float* __restrict__ xin,
                                                   float* __restrict__ out){
  __shared__ ushort Bt[64*256];
  const int K = 256;
  const int t = threadIdx.x, w = t >> 6, lane = t & 63;
  const int li = lane & 15, quad = lane >> 4;
  const int tm = blockIdx.x & 63, tn = blockIdx.x >> 6;   // 64 x 4
  const int batch = blockIdx.y;
  A   += (size_t)batch * NSP * CCH;
  xin += (size_t)batch * CCH * NSP;
  out += (size_t)batch * CCH * NSP;
  const int m0 = tm*64 + w*16;
  const int nb = tn*64;

  #pragma unroll
  for (int i = 0; i < 8; i++){
    const int id = t + 256*i;
    const int row = id >> 5, gg = id & 31;
    *(ushort8*)&Bt[row*256 + (gg ^ (row & 31))*8] =
      *(const ushort8*)(Bm + (size_t)(nb + row)*K + gg*8);
  }
  short8 afr[8];
  #pragma unroll
  for (int kk = 0; kk < 8; kk++)
    afr[kk] = *(const short8*)(A + (size_t)(m0 + li)*K + kk*32 + quad*8);
  __syncthreads();

  #pragma unroll
  for (int nt = 0; nt < 4; nt++){
    f32x4 acc = {0.f,0.f,0.f,0.f};
    const int d = nb + nt*16 + li;
    const int rowl = nt*16 + li;
    #pragma unroll
    for (int kk = 0; kk < 8; kk++){
      short8 bfr = *(const short8*)&Bt[rowl*256 + ((4*kk + quad) ^ (rowl & 31))*8];
      acc = __builtin_amdgcn_mfma_f32_16x16x32_bf16(afr[kk], bfr, acc, 0, 0, 0);
    }
    const float bias = b3[d];
    const size_t idx = (size_t)d*NSP + m0 + quad*4;
    f32x4 xv = *(const f32x4*)(xin + idx);
    f32x4 ov;
    #pragma unroll
    for (int r = 0; r < 4; r++) ov[r] = acc[r] + bias + xv[r];
    *(f32x4*)(out + idx) = ov;
  }
}

extern "C" void kernel_launch(void* const* d_in, const int* in_sizes, int n_in,
                              void* d_out, int out_size, void* d_ws, size_t ws_size,
                              hipStream_t stream){
  const float* x     = (const float*)d_in[0];
  const float* gamma = (const float*)d_in[1];
  const float* beta  = (const float*)d_in[2];
  const float* w0    = (const float*)d_in[3];
  const float* b0    = (const float*)d_in[4];
  const float* w1    = (const float*)d_in[5];
  const float* b1    = (const float*)d_in[6];
  const float* w2    = (const float*)d_in[7];
  const float* b2    = (const float*)d_in[8];
  const float* w3    = (const float*)d_in[9];
  const float* b3    = (const float*)d_in[10];
  float* out = (float*)d_out;

  ushort* h_t  = (ushort*)d_out;                  // d_out scratch (dead later)
  ushort* ph01 = (ushort*)d_out;                  // partial slots 0,1 (16 MB)
  ushort* q_t = (ushort*)d_ws;
  ushort* k_t = q_t + TEN;                        // later reused as Oc
  ushort* v   = k_t + TEN;
  ushort* wT  = v + TEN;                          // 4 x 65536 bf16
  float* stats = (float*)(wT + 4*65536);
  float* lbuf  = stats + 256;                     // up to 4*16384 f32
  ushort* ph23 = (ushort*)(lbuf + 4*BB*NSP);      // partial slots 2,3 (16 MB)

  const size_t need4 = ((3*TEN + 4*65536)*2) + (256 + 4*BB*NSP)*4 + 2*TEN*2;
  const int ks = (ws_size >= need4) ? 4 : 2;
  const int iters = NSP / (ks * 32);

  transpose_w4_k<<<dim3(16,4), 256, 0, stream>>>(w0, w1, w2, w3, wT);
  gn_stats_k<<<128, 256, 0, stream>>>(x, stats);
  gn_apply_k<<<dim3(64,4,4), 256, 0, stream>>>(x, stats, gamma, beta, h_t);

  const long HS = (long)NSP * CCH;
  gemm_lds_k<<<dim3(256, BB), 256, 0, stream>>>(wT,         h_t, q_t, 256, 4096, 0, HS, HS, b0, nullptr);
  gemm_lds_k<<<dim3(256, BB), 256, 0, stream>>>(wT+65536,   h_t, k_t, 256, 4096, 0, HS, HS, b1, nullptr);
  gemm_lds_k<<<dim3(256, BB), 256, 0, stream>>>(h_t, wT+2*65536, v, 4096, 256, HS, 0, HS, nullptr, b2);

  attn_k<<<BB*64*ks, 256, 0, stream>>>(q_t, k_t, v, ph01, ph23, lbuf, iters);

  ushort* Oc = k_t;                               // k_t dead after attn
  combine_k<<<2048, 256, 0, stream>>>(ph01, ph23, lbuf, Oc, ks);
  gemm_proj_k<<<dim3(256, BB), 256, 0, stream>>>(Oc, wT + 3*65536, b3, x, out);
}

// Round 7
// 274.980 us; speedup vs baseline: 1.8140x; 1.8140x over previous
//
#include <hip/hip_runtime.h>
#include <math.h>

// B=4, C=256, N=H*W=4096, G=32. All inputs/output FLOAT32; bf16 internally.
// out = x + nin3( attn( nin0/1/2( groupnorm(x) ) ) )
//
// Attention core: 32x32x16 MFMA, 32 queries/wave, Q-block 128, key-tile 32.
// S^T = K*Q^T (C/D: col=lane&31=q, rows=keys) -> fixed-M exp2 softmax ->
// P to A-operand via one shfl_xor(32) half-exchange (no LDS round-trip) ->
// O[q][c] += P*V. Partials (un-normalized, additive thanks to fixed-M) in
// [c][q] layout; combine kernel transposes + normalizes; gemm_proj finishes.

typedef short short8    __attribute__((ext_vector_type(8)));
typedef ushort ushort8  __attribute__((ext_vector_type(8)));
typedef float f32x4     __attribute__((ext_vector_type(4)));
typedef float f32x16    __attribute__((ext_vector_type(16)));

#define BB 4
#define CCH 256
#define NSP 4096
#define TEN ((size_t)BB * NSP * CCH)

__device__ __forceinline__ float b2f(ushort h){
  unsigned int u = ((unsigned int)h) << 16;
  float f; __builtin_memcpy(&f, &u, 4); return f;
}
__device__ __forceinline__ ushort f2b(float f){
  unsigned int u; __builtin_memcpy(&u, &f, 4);
  u += 0x7fffu + ((u >> 16) & 1u);   // RTNE
  return (ushort)(u >> 16);
}
__device__ __forceinline__ unsigned int pk2(float a, float b){
  return (unsigned int)f2b(a) | ((unsigned int)f2b(b) << 16);
}

// ---------------- GroupNorm stats ----------------
__global__ __launch_bounds__(256) void gn_stats_k(const float* __restrict__ x,
                                                  float* __restrict__ stats){
  const int bg = blockIdx.x;
  const f32x4* p = (const f32x4*)(x + (size_t)bg * 32768);
  float s = 0.f, s2 = 0.f;
  for (int i = threadIdx.x; i < 8192; i += 256){
    f32x4 v = p[i];
    #pragma unroll
    for (int j = 0; j < 4; j++){ s += v[j]; s2 += v[j]*v[j]; }
  }
  #pragma unroll
  for (int off = 32; off >= 1; off >>= 1){
    s  += __shfl_down(s,  off, 64);
    s2 += __shfl_down(s2, off, 64);
  }
  __shared__ float red[8];
  const int w = threadIdx.x >> 6;
  if ((threadIdx.x & 63) == 0){ red[w*2] = s; red[w*2+1] = s2; }
  __syncthreads();
  if (threadIdx.x == 0){
    float S  = red[0]+red[2]+red[4]+red[6];
    float S2 = red[1]+red[3]+red[5]+red[7];
    float mean = S * (1.f/32768.f);
    float var  = fmaxf(S2 * (1.f/32768.f) - mean*mean, 0.f);
    stats[bg*2]   = mean;
    stats[bg*2+1] = rsqrtf(var + 1e-6f);
  }
}

// ------- GN apply + transpose + cast: x[b][c][n] f32 -> h_t[b][n][c] bf16 ------
__global__ __launch_bounds__(256) void gn_apply_k(const float* __restrict__ x,
                                                  const float* __restrict__ stats,
                                                  const float* __restrict__ gamma,
                                                  const float* __restrict__ beta,
                                                  ushort* __restrict__ h_t){
  __shared__ ushort tile[64][72];
  const int b = blockIdx.z, c0 = blockIdx.y*64, n0 = blockIdx.x*64;
  const int t = threadIdx.x;
  #pragma unroll
  for (int p = 0; p < 2; p++){
    const int cl = p*32 + (t >> 3);
    const int nc = (t & 7) * 8;
    const int c = c0 + cl;
    const float mean = stats[(b*32 + (c>>3))*2];
    const float rstd = stats[(b*32 + (c>>3))*2 + 1];
    const float sc = rstd * gamma[c];
    const float sh = beta[c] - mean * sc;
    const float* xr = x + ((size_t)b*CCH + c)*NSP + n0 + nc;
    f32x4 a = *(const f32x4*)xr;
    f32x4 d = *(const f32x4*)(xr + 4);
    #pragma unroll
    for (int j = 0; j < 4; j++){
      tile[nc + j][cl]     = f2b(a[j]*sc + sh);
      tile[nc + 4 + j][cl] = f2b(d[j]*sc + sh);
    }
  }
  __syncthreads();
  #pragma unroll
  for (int p = 0; p < 2; p++){
    const int nl = p*32 + (t >> 3);
    const int cc = (t & 7) * 8;
    ushort8 ov;
    #pragma unroll
    for (int j = 0; j < 8; j++) ov[j] = tile[nl][cc + j];
    *(ushort8*)(h_t + ((size_t)b*NSP + n0 + nl)*CCH + c0 + cc) = ov;
  }
}

// ------- weight transpose + cast ------------------------------------------------
__global__ __launch_bounds__(256) void transpose_w4_k(const float* __restrict__ w0,
                                                      const float* __restrict__ w1,
                                                      const float* __restrict__ w2,
                                                      const float* __restrict__ w3,
                                                      ushort* __restrict__ wT){
  __shared__ ushort tile[64][72];
  const float* w = (blockIdx.y==0) ? w0 : (blockIdx.y==1) ? w1 : (blockIdx.y==2) ? w2 : w3;
  ushort* dst = wT + (size_t)blockIdx.y * 65536;
  const int tb = blockIdx.x;
  const int r0 = (tb >> 2) * 64, c0 = (tb & 3) * 64;
  const int t = threadIdx.x;
  #pragma unroll
  for (int p = 0; p < 2; p++){
    const int r = p*32 + (t >> 3), cc = (t & 7)*8;
    const float* wr = w + (size_t)(r0 + r)*256 + c0 + cc;
    f32x4 a = *(const f32x4*)wr;
    f32x4 d = *(const f32x4*)(wr + 4);
    #pragma unroll
    for (int j = 0; j < 4; j++){
      tile[r][cc + j]     = f2b(a[j]);
      tile[r][cc + 4 + j] = f2b(d[j]);
    }
  }
  __syncthreads();
  #pragma unroll
  for (int p = 0; p < 2; p++){
    const int r = p*32 + (t >> 3), cc = (t & 7)*8;
    ushort8 ov;
    #pragma unroll
    for (int j = 0; j < 8; j++) ov[j] = tile[cc + j][r];
    *(ushort8*)(dst + (size_t)(c0 + r)*256 + r0 + cc) = ov;
  }
}

// ------------- GEMM with LDS-staged B-tile (swizzled) --------------------------
__global__ __launch_bounds__(256) void gemm_lds_k(const ushort* __restrict__ A,
                                                  const ushort* __restrict__ B,
                                                  ushort* __restrict__ OutT,
                                                  int M, int N,
                                                  long aStride, long bStride, long oStride,
                                                  const float* __restrict__ biasM,
                                                  const float* __restrict__ biasN){
  __shared__ ushort Bt[64*256];
  const int K = 256;
  const int t = threadIdx.x, w = t >> 6, lane = t & 63;
  const int li = lane & 15, quad = lane >> 4;
  const int m64 = M >> 6;
  const int tm = blockIdx.x % m64, tn = blockIdx.x / m64;
  const int batch = blockIdx.y;
  A    += (size_t)batch * aStride;
  B    += (size_t)batch * bStride;
  OutT += (size_t)batch * oStride;
  const int m0 = tm*64 + w*16;
  const int nb = tn*64;

  #pragma unroll
  for (int i = 0; i < 8; i++){
    const int id = t + 256*i;
    const int row = id >> 5, gg = id & 31;
    *(ushort8*)&Bt[row*256 + (gg ^ (row & 31))*8] =
      *(const ushort8*)(B + (size_t)(nb + row)*K + gg*8);
  }
  short8 afr[8];
  #pragma unroll
  for (int kk = 0; kk < 8; kk++)
    afr[kk] = *(const short8*)(A + (size_t)(m0 + li)*K + kk*32 + quad*8);
  __syncthreads();

  #pragma unroll
  for (int nt = 0; nt < 4; nt++){
    f32x4 acc = {0.f,0.f,0.f,0.f};
    const int n = nb + nt*16 + li;
    const int rowl = nt*16 + li;
    #pragma unroll
    for (int kk = 0; kk < 8; kk++){
      short8 bfr = *(const short8*)&Bt[rowl*256 + ((4*kk + quad) ^ (rowl & 31))*8];
      acc = __builtin_amdgcn_mfma_f32_16x16x32_bf16(afr[kk], bfr, acc, 0, 0, 0);
    }
    const float bn = biasN ? biasN[n] : 0.f;
    ushort ov[4];
    #pragma unroll
    for (int r = 0; r < 4; r++){
      const float bm = biasM ? biasM[m0 + quad*4 + r] : 0.f;
      ov[r] = f2b(acc[r] + bm + bn);
    }
    *(uint2*)(OutT + (size_t)n*M + m0 + quad*4) = *(uint2*)ov;
  }
}

// ---------------- 32x32x16 fixed-M flash attention -----------------------------
// grid 128*ks: qt = bx&31 (Q-block 128), b = (bx>>5)&3, s = bx>>7.
// 4 waves; wave w owns queries n0 + w*32 + (lane&31).
__global__ __launch_bounds__(256, 2) void attn32_k(const ushort* __restrict__ qg,
                                                   const ushort* __restrict__ kg,
                                                   const ushort* __restrict__ vg,
                                                   ushort* __restrict__ ph01,
                                                   ushort* __restrict__ ph23,
                                                   float* __restrict__ lbuf,
                                                   int iters){
  __shared__ ushort Kt[32*260];            // [key][c], pad 4 -> 2-way-free reads
  __shared__ ushort Vt[256*36];            // [c][key], pad 4 -> 2-way-free reads

  const int t = threadIdx.x, w = t >> 6, lane = t & 63;
  const int cl = lane & 31, h = lane >> 5;
  const int bx = blockIdx.x;
  const int qt = bx & 31, b = (bx >> 5) & 3, s = bx >> 7;
  const int n0 = qt * 128;
  const int qb = n0 + w*32;                // wave's query base
  const int keybase = s * (iters * 32);

  const ushort* kb = kg + (size_t)b*NSP*CCH;
  const ushort* vb = vg + (size_t)b*CCH*NSP;

  // Q as B-operand: lane holds q = qb+cl, channels st*16 + h*8 + j
  short8 qf[16];
  {
    const ushort* qrow = qg + ((size_t)b*NSP + qb + cl)*CCH + h*8;
    #pragma unroll
    for (int st = 0; st < 16; st++) qf[st] = *(const short8*)(qrow + st*16);
  }

  f32x16 oacc[8];
  #pragma unroll
  for (int i = 0; i < 8; i++) oacc[i] = (f32x16)(0.f);
  float l_i = 0.f;
  const float c1 = 0.0625f * 1.44269504088896f;   // C^-0.5 * log2(e)
  const float M2 = 24.f;

  for (int it = 0; it < iters; it++){
    const int key0 = keybase + it*32;
    __syncthreads();
    #pragma unroll
    for (int i = 0; i < 4; i++){
      const int id = t + 256*i;
      ushort8 kv = *(const ushort8*)(kb + (size_t)(key0 + (id>>5))*CCH + (id&31)*8);
      ushort8 vv = *(const ushort8*)(vb + (size_t)(id>>2)*NSP + key0 + (id&3)*8);
      *(ushort8*)&Kt[(id>>5)*260 + (id&31)*8] = kv;
      *(ushort8*)&Vt[(id>>2)*36  + (id&3)*8]  = vv;
    }
    __syncthreads();

    // S^T = K * Q^T : A = K (row=lane&31=key, k=ch h*8+j), B = Q (regs)
    f32x16 sacc = (f32x16)(0.f);
    #pragma unroll
    for (int st = 0; st < 16; st++){
      short8 kf = *(const short8*)&Kt[cl*260 + st*16 + h*8];
      sacc = __builtin_amdgcn_mfma_f32_32x32x16_bf16(kf, qf[st], sacc, 0, 0, 0);
    }

    // fixed-M softmax; C/D: lane holds q=cl, key(reg r) = (r&3)+8*(r>>2)+4h
    unsigned int grp[4][2];
    #pragma unroll
    for (int m = 0; m < 4; m++){
      float p0 = __builtin_amdgcn_exp2f(fminf(sacc[4*m+0]*c1 - M2, 30.f));
      float p1 = __builtin_amdgcn_exp2f(fminf(sacc[4*m+1]*c1 - M2, 30.f));
      float p2 = __builtin_amdgcn_exp2f(fminf(sacc[4*m+2]*c1 - M2, 30.f));
      float p3 = __builtin_amdgcn_exp2f(fminf(sacc[4*m+3]*c1 - M2, 30.f));
      l_i += (p0 + p1) + (p2 + p3);
      grp[m][0] = pk2(p0, p1);
      grp[m][1] = pk2(p2, p3);
    }
    // half-exchange: build P A-frags (lane q=cl, k-chunk h*8+j per 16-key step)
    unsigned int sa0 = h ? grp[0][0] : grp[1][0];
    unsigned int sa1 = h ? grp[0][1] : grp[1][1];
    unsigned int sb0 = h ? grp[2][0] : grp[3][0];
    unsigned int sb1 = h ? grp[2][1] : grp[3][1];
    unsigned int ra0 = __shfl_xor((int)sa0, 32, 64);
    unsigned int ra1 = __shfl_xor((int)sa1, 32, 64);
    unsigned int rb0 = __shfl_xor((int)sb0, 32, 64);
    unsigned int rb1 = __shfl_xor((int)sb1, 32, 64);
    unsigned int f0[4], f1[4];
    if (h == 0){
      f0[0]=grp[0][0]; f0[1]=grp[0][1]; f0[2]=ra0; f0[3]=ra1;
      f1[0]=grp[2][0]; f1[1]=grp[2][1]; f1[2]=rb0; f1[3]=rb1;
    } else {
      f0[0]=ra0; f0[1]=ra1; f0[2]=grp[1][0]; f0[3]=grp[1][1];
      f1[0]=rb0; f1[1]=rb1; f1[2]=grp[3][0]; f1[3]=grp[3][1];
    }
    short8 pf0, pf1;
    __builtin_memcpy(&pf0, f0, 16);
    __builtin_memcpy(&pf1, f1, 16);

    // O[q][c] += P * V : B = V (lane c=ct*32+cl, keys st*16 + h*8 + j)
    #pragma unroll
    for (int ct = 0; ct < 8; ct++){
      short8 v0 = *(const short8*)&Vt[(ct*32 + cl)*36 + h*8];
      short8 v1 = *(const short8*)&Vt[(ct*32 + cl)*36 + 16 + h*8];
      oacc[ct] = __builtin_amdgcn_mfma_f32_32x32x16_bf16(pf0, v0, oacc[ct], 0, 0, 0);
      oacc[ct] = __builtin_amdgcn_mfma_f32_32x32x16_bf16(pf1, v1, oacc[ct], 0, 0, 0);
    }
  }

  // partial store: PhT[s][b][c][q] (lane holds col c = ct*32+cl, 16 q rows)
  ushort* ps = (s < 2) ? (ph01 + (size_t)s*TEN) : (ph23 + (size_t)(s-2)*TEN);
  ps += (size_t)b * NSP * CCH;
  #pragma unroll
  for (int ct = 0; ct < 8; ct++){
    const size_t crow = (size_t)(ct*32 + cl) * NSP;
    #pragma unroll
    for (int m = 0; m < 4; m++){
      unsigned int d0 = pk2(oacc[ct][4*m+0], oacc[ct][4*m+1]);
      unsigned int d1 = pk2(oacc[ct][4*m+2], oacc[ct][4*m+3]);
      uint2 dv; dv.x = d0; dv.y = d1;
      *(uint2*)(ps + crow + qb + 8*m + 4*h) = dv;
    }
  }
  l_i += __shfl_xor(l_i, 32, 64);
  if (h == 0)
    lbuf[(size_t)s*BB*NSP + (size_t)b*NSP + qb + cl] = l_i;
}

// ---------------- combine: sum ks partials, normalize, transpose to Oc[q][c] ---
__global__ __launch_bounds__(256) void combine_k(const ushort* __restrict__ ph01,
                                                 const ushort* __restrict__ ph23,
                                                 const float* __restrict__ lbuf,
                                                 ushort* __restrict__ Oc, int ks){
  __shared__ ushort T[64*66];
  const int t = threadIdx.x;
  const int q0 = blockIdx.x * 64, c0 = blockIdx.y * 64, b = blockIdx.z;
  const int ql = t & 63, cs = t >> 6;           // lanes along q (coalesced reads)
  float suml = 0.f;
  for (int sp = 0; sp < ks; sp++) suml += lbuf[(size_t)sp*BB*NSP + (size_t)b*NSP + q0 + ql];
  const float rl = 1.f / suml;
  #pragma unroll
  for (int ci = 0; ci < 16; ci++){
    const int c = cs*16 + ci;
    float acc = 0.f;
    for (int sp = 0; sp < ks; sp++){
      const ushort* pp = (sp < 2) ? (ph01 + (size_t)sp*TEN) : (ph23 + (size_t)(sp-2)*TEN);
      acc += b2f(pp[((size_t)b*CCH + c0 + c)*NSP + q0 + ql]);
    }
    T[ql*66 + c] = f2b(acc * rl);
  }
  __syncthreads();
  const int q2 = t >> 2, ch = (t & 3) * 16;
  ushort8 o0, o1;
  #pragma unroll
  for (int j = 0; j < 8; j++){ o0[j] = T[q2*66 + ch + j]; o1[j] = T[q2*66 + ch + 8 + j]; }
  ushort* dst = Oc + ((size_t)b*NSP + q0 + q2)*CCH + c0 + ch;
  *(ushort8*)dst = o0;
  *(ushort8*)(dst + 8) = o1;
}

// ---------------- final projection + bias + residual (f32 out) -----------------
__global__ __launch_bounds__(256) void gemm_proj_k(const ushort* __restrict__ A,
                                                   const ushort* __restrict__ Bm,
                                                   const float* __restrict__ b3,
                                                   const float* __restrict__ xin,
                                                   float* __restrict__ out){
  __shared__ ushort Bt[64*256];
  const int K = 256;
  const int t = threadIdx.x, w = t >> 6, lane = t & 63;
  const int li = lane & 15, quad = lane >> 4;
  const int tm = blockIdx.x & 63, tn = blockIdx.x >> 6;
  const int batch = blockIdx.y;
  A   += (size_t)batch * NSP * CCH;
  xin += (size_t)batch * CCH * NSP;
  out += (size_t)batch * CCH * NSP;
  const int m0 = tm*64 + w*16;
  const int nb = tn*64;

  #pragma unroll
  for (int i = 0; i < 8; i++){
    const int id = t + 256*i;
    const int row = id >> 5, gg = id & 31;
    *(ushort8*)&Bt[row*256 + (gg ^ (row & 31))*8] =
      *(const ushort8*)(Bm + (size_t)(nb + row)*K + gg*8);
  }
  short8 afr[8];
  #pragma unroll
  for (int kk = 0; kk < 8; kk++)
    afr[kk] = *(const short8*)(A + (size_t)(m0 + li)*K + kk*32 + quad*8);
  __syncthreads();

  #pragma unroll
  for (int nt = 0; nt < 4; nt++){
    f32x4 acc = {0.f,0.f,0.f,0.f};
    const int d = nb + nt*16 + li;
    const int rowl = nt*16 + li;
    #pragma unroll
    for (int kk = 0; kk < 8; kk++){
      short8 bfr = *(const short8*)&Bt[rowl*256 + ((4*kk + quad) ^ (rowl & 31))*8];
      acc = __builtin_amdgcn_mfma_f32_16x16x32_bf16(afr[kk], bfr, acc, 0, 0, 0);
    }
    const float bias = b3[d];
    const size_t idx = (size_t)d*NSP + m0 + quad*4;
    f32x4 xv = *(const f32x4*)(xin + idx);
    f32x4 ov;
    #pragma unroll
    for (int r = 0; r < 4; r++) ov[r] = acc[r] + bias + xv[r];
    *(f32x4*)(out + idx) = ov;
  }
}

extern "C" void kernel_launch(void* const* d_in, const int* in_sizes, int n_in,
                              void* d_out, int out_size, void* d_ws, size_t ws_size,
                              hipStream_t stream){
  const float* x     = (const float*)d_in[0];
  const float* gamma = (const float*)d_in[1];
  const float* beta  = (const float*)d_in[2];
  const float* w0    = (const float*)d_in[3];
  const float* b0    = (const float*)d_in[4];
  const float* w1    = (const float*)d_in[5];
  const float* b1    = (const float*)d_in[6];
  const float* w2    = (const float*)d_in[7];
  const float* b2    = (const float*)d_in[8];
  const float* w3    = (const float*)d_in[9];
  const float* b3    = (const float*)d_in[10];
  float* out = (float*)d_out;

  ushort* h_t  = (ushort*)d_out;                  // d_out scratch (dead later)
  ushort* ph01 = (ushort*)d_out;                  // partial splits 0,1 (16 MB)
  ushort* q_t = (ushort*)d_ws;
  ushort* k_t = q_t + TEN;                        // later reused as Oc
  ushort* v   = k_t + TEN;
  ushort* wT  = v + TEN;                          // 4 x 65536 bf16
  float* stats = (float*)(wT + 4*65536);
  float* lbuf  = stats + 256;                     // up to 4*16384 f32
  ushort* ph23 = (ushort*)(lbuf + 4*BB*NSP);      // partial splits 2,3 (16 MB)

  const size_t need4 = ((3*TEN + 4*65536)*2) + (256 + 4*BB*NSP)*4 + 2*TEN*2;
  const int ks = (ws_size >= need4) ? 4 : 2;
  const int iters = NSP / (ks * 32);

  transpose_w4_k<<<dim3(16,4), 256, 0, stream>>>(w0, w1, w2, w3, wT);
  gn_stats_k<<<128, 256, 0, stream>>>(x, stats);
  gn_apply_k<<<dim3(64,4,4), 256, 0, stream>>>(x, stats, gamma, beta, h_t);

  const long HS = (long)NSP * CCH;
  gemm_lds_k<<<dim3(256, BB), 256, 0, stream>>>(wT,         h_t, q_t, 256, 4096, 0, HS, HS, b0, nullptr);
  gemm_lds_k<<<dim3(256, BB), 256, 0, stream>>>(wT+65536,   h_t, k_t, 256, 4096, 0, HS, HS, b1, nullptr);
  gemm_lds_k<<<dim3(256, BB), 256, 0, stream>>>(h_t, wT+2*65536, v, 4096, 256, HS, 0, HS, nullptr, b2);

  attn32_k<<<128*ks, 256, 0, stream>>>(q_t, k_t, v, ph01, ph23, lbuf, iters);

  ushort* Oc = k_t;                               // k_t dead after attn
  combine_k<<<dim3(64, 4, BB), 256, 0, stream>>>(ph01, ph23, lbuf, Oc, ks);
  gemm_proj_k<<<dim3(256, BB), 256, 0, stream>>>(Oc, wT + 3*65536, b3, x, out);
}

// Round 8
// 268.976 us; speedup vs baseline: 1.8545x; 1.0223x over previous
//
#include <hip/hip_runtime.h>
#include <math.h>

// B=4, C=256, N=H*W=4096, G=32. All inputs/output FLOAT32; bf16 internally.
// out = x + nin3( attn( nin0/1/2( groupnorm(x) ) ) )
//
// Attention: 32x32x16 MFMA, 32 q/wave, Q-block 128, key-tile 32, fixed-M
// softmax (M2=24, validated R6/R7), ks-way key split with additive partials.
// R8: K-tile register prefetch (latency hidden behind compute) + XCD-aware
// block swizzle (same-(b,s) blocks share an XCD's L2).

typedef short short8    __attribute__((ext_vector_type(8)));
typedef ushort ushort8  __attribute__((ext_vector_type(8)));
typedef float f32x4     __attribute__((ext_vector_type(4)));
typedef float f32x16    __attribute__((ext_vector_type(16)));

#define BB 4
#define CCH 256
#define NSP 4096
#define TEN ((size_t)BB * NSP * CCH)

__device__ __forceinline__ float b2f(ushort h){
  unsigned int u = ((unsigned int)h) << 16;
  float f; __builtin_memcpy(&f, &u, 4); return f;
}
__device__ __forceinline__ ushort f2b(float f){
  unsigned int u; __builtin_memcpy(&u, &f, 4);
  u += 0x7fffu + ((u >> 16) & 1u);   // RTNE
  return (ushort)(u >> 16);
}
__device__ __forceinline__ unsigned int pk2(float a, float b){
  return (unsigned int)f2b(a) | ((unsigned int)f2b(b) << 16);
}

// ---------------- GroupNorm stats ----------------
__global__ __launch_bounds__(256) void gn_stats_k(const float* __restrict__ x,
                                                  float* __restrict__ stats){
  const int bg = blockIdx.x;
  const f32x4* p = (const f32x4*)(x + (size_t)bg * 32768);
  float s = 0.f, s2 = 0.f;
  for (int i = threadIdx.x; i < 8192; i += 256){
    f32x4 v = p[i];
    #pragma unroll
    for (int j = 0; j < 4; j++){ s += v[j]; s2 += v[j]*v[j]; }
  }
  #pragma unroll
  for (int off = 32; off >= 1; off >>= 1){
    s  += __shfl_down(s,  off, 64);
    s2 += __shfl_down(s2, off, 64);
  }
  __shared__ float red[8];
  const int w = threadIdx.x >> 6;
  if ((threadIdx.x & 63) == 0){ red[w*2] = s; red[w*2+1] = s2; }
  __syncthreads();
  if (threadIdx.x == 0){
    float S  = red[0]+red[2]+red[4]+red[6];
    float S2 = red[1]+red[3]+red[5]+red[7];
    float mean = S * (1.f/32768.f);
    float var  = fmaxf(S2 * (1.f/32768.f) - mean*mean, 0.f);
    stats[bg*2]   = mean;
    stats[bg*2+1] = rsqrtf(var + 1e-6f);
  }
}

// ------- GN apply + transpose + cast: x[b][c][n] f32 -> h_t[b][n][c] bf16 ------
__global__ __launch_bounds__(256) void gn_apply_k(const float* __restrict__ x,
                                                  const float* __restrict__ stats,
                                                  const float* __restrict__ gamma,
                                                  const float* __restrict__ beta,
                                                  ushort* __restrict__ h_t){
  __shared__ ushort tile[64][72];
  const int b = blockIdx.z, c0 = blockIdx.y*64, n0 = blockIdx.x*64;
  const int t = threadIdx.x;
  #pragma unroll
  for (int p = 0; p < 2; p++){
    const int cl = p*32 + (t >> 3);
    const int nc = (t & 7) * 8;
    const int c = c0 + cl;
    const float mean = stats[(b*32 + (c>>3))*2];
    const float rstd = stats[(b*32 + (c>>3))*2 + 1];
    const float sc = rstd * gamma[c];
    const float sh = beta[c] - mean * sc;
    const float* xr = x + ((size_t)b*CCH + c)*NSP + n0 + nc;
    f32x4 a = *(const f32x4*)xr;
    f32x4 d = *(const f32x4*)(xr + 4);
    #pragma unroll
    for (int j = 0; j < 4; j++){
      tile[nc + j][cl]     = f2b(a[j]*sc + sh);
      tile[nc + 4 + j][cl] = f2b(d[j]*sc + sh);
    }
  }
  __syncthreads();
  #pragma unroll
  for (int p = 0; p < 2; p++){
    const int nl = p*32 + (t >> 3);
    const int cc = (t & 7) * 8;
    ushort8 ov;
    #pragma unroll
    for (int j = 0; j < 8; j++) ov[j] = tile[nl][cc + j];
    *(ushort8*)(h_t + ((size_t)b*NSP + n0 + nl)*CCH + c0 + cc) = ov;
  }
}

// ------- weight transpose + cast ------------------------------------------------
__global__ __launch_bounds__(256) void transpose_w4_k(const float* __restrict__ w0,
                                                      const float* __restrict__ w1,
                                                      const float* __restrict__ w2,
                                                      const float* __restrict__ w3,
                                                      ushort* __restrict__ wT){
  __shared__ ushort tile[64][72];
  const float* w = (blockIdx.y==0) ? w0 : (blockIdx.y==1) ? w1 : (blockIdx.y==2) ? w2 : w3;
  ushort* dst = wT + (size_t)blockIdx.y * 65536;
  const int tb = blockIdx.x;
  const int r0 = (tb >> 2) * 64, c0 = (tb & 3) * 64;
  const int t = threadIdx.x;
  #pragma unroll
  for (int p = 0; p < 2; p++){
    const int r = p*32 + (t >> 3), cc = (t & 7)*8;
    const float* wr = w + (size_t)(r0 + r)*256 + c0 + cc;
    f32x4 a = *(const f32x4*)wr;
    f32x4 d = *(const f32x4*)(wr + 4);
    #pragma unroll
    for (int j = 0; j < 4; j++){
      tile[r][cc + j]     = f2b(a[j]);
      tile[r][cc + 4 + j] = f2b(d[j]);
    }
  }
  __syncthreads();
  #pragma unroll
  for (int p = 0; p < 2; p++){
    const int r = p*32 + (t >> 3), cc = (t & 7)*8;
    ushort8 ov;
    #pragma unroll
    for (int j = 0; j < 8; j++) ov[j] = tile[cc + j][r];
    *(ushort8*)(dst + (size_t)(c0 + r)*256 + r0 + cc) = ov;
  }
}

// ------------- GEMM with LDS-staged B-tile (swizzled) --------------------------
__global__ __launch_bounds__(256) void gemm_lds_k(const ushort* __restrict__ A,
                                                  const ushort* __restrict__ B,
                                                  ushort* __restrict__ OutT,
                                                  int M, int N,
                                                  long aStride, long bStride, long oStride,
                                                  const float* __restrict__ biasM,
                                                  const float* __restrict__ biasN){
  __shared__ ushort Bt[64*256];
  const int K = 256;
  const int t = threadIdx.x, w = t >> 6, lane = t & 63;
  const int li = lane & 15, quad = lane >> 4;
  const int m64 = M >> 6;
  const int tm = blockIdx.x % m64, tn = blockIdx.x / m64;
  const int batch = blockIdx.y;
  A    += (size_t)batch * aStride;
  B    += (size_t)batch * bStride;
  OutT += (size_t)batch * oStride;
  const int m0 = tm*64 + w*16;
  const int nb = tn*64;

  #pragma unroll
  for (int i = 0; i < 8; i++){
    const int id = t + 256*i;
    const int row = id >> 5, gg = id & 31;
    *(ushort8*)&Bt[row*256 + (gg ^ (row & 31))*8] =
      *(const ushort8*)(B + (size_t)(nb + row)*K + gg*8);
  }
  short8 afr[8];
  #pragma unroll
  for (int kk = 0; kk < 8; kk++)
    afr[kk] = *(const short8*)(A + (size_t)(m0 + li)*K + kk*32 + quad*8);
  __syncthreads();

  #pragma unroll
  for (int nt = 0; nt < 4; nt++){
    f32x4 acc = {0.f,0.f,0.f,0.f};
    const int n = nb + nt*16 + li;
    const int rowl = nt*16 + li;
    #pragma unroll
    for (int kk = 0; kk < 8; kk++){
      short8 bfr = *(const short8*)&Bt[rowl*256 + ((4*kk + quad) ^ (rowl & 31))*8];
      acc = __builtin_amdgcn_mfma_f32_16x16x32_bf16(afr[kk], bfr, acc, 0, 0, 0);
    }
    const float bn = biasN ? biasN[n] : 0.f;
    ushort ov[4];
    #pragma unroll
    for (int r = 0; r < 4; r++){
      const float bm = biasM ? biasM[m0 + quad*4 + r] : 0.f;
      ov[r] = f2b(acc[r] + bm + bn);
    }
    *(uint2*)(OutT + (size_t)n*M + m0 + quad*4) = *(uint2*)ov;
  }
}

// ---------------- 32x32x16 fixed-M flash attention, K-prefetch -----------------
// grid 128*ks, bx = qt*(4*ks) + s*4 + b  (same (b,s) -> same XCD via bx%8).
__global__ __launch_bounds__(256, 2) void attn32_k(const ushort* __restrict__ qg,
                                                   const ushort* __restrict__ kg,
                                                   const ushort* __restrict__ vg,
                                                   ushort* __restrict__ ph01,
                                                   ushort* __restrict__ ph23,
                                                   float* __restrict__ lbuf,
                                                   int iters, int ks4){
  __shared__ ushort Kt[32*260];            // [key][c], pad 4 -> 2-way-free reads
  __shared__ ushort Vt[256*36];            // [c][key], pad 4 -> 2-way-free reads

  const int t = threadIdx.x, lane = t & 63;
  const int cl = lane & 31, h = lane >> 5;
  const int bx = blockIdx.x;
  const int qt = bx / ks4;                 // ks4 = 4*ks
  const int r  = bx % ks4;
  const int s  = r >> 2, b = r & 3;
  const int n0 = qt * 128;
  const int w = t >> 6;
  const int qb = n0 + w*32;                // wave's query base
  const int keybase = s * (iters * 32);

  const ushort* kb = kg + (size_t)b*NSP*CCH;
  const ushort* vb = vg + (size_t)b*CCH*NSP;

  // Q as B-operand: lane holds q = qb+cl, channels st*16 + h*8 + j
  short8 qf[16];
  {
    const ushort* qrow = qg + ((size_t)b*NSP + qb + cl)*CCH + h*8;
    #pragma unroll
    for (int st = 0; st < 16; st++) qf[st] = *(const short8*)(qrow + st*16);
  }

  f32x16 oacc[8];
  #pragma unroll
  for (int i = 0; i < 8; i++) oacc[i] = (f32x16)(0.f);
  float l_i = 0.f;
  const float c1 = 0.0625f * 1.44269504088896f;   // C^-0.5 * log2(e)
  const float M2 = 24.f;

  // prologue: prefetch K tile 0 into registers
  ushort8 kreg[4];
  #pragma unroll
  for (int i = 0; i < 4; i++){
    const int id = t + 256*i;
    kreg[i] = *(const ushort8*)(kb + (size_t)(keybase + (id>>5))*CCH + (id&31)*8);
  }

  for (int it = 0; it < iters; it++){
    const int key0 = keybase + it*32;
    __syncthreads();                       // prev iter's Kt/Vt reads done
    // V loads issued first; K LDS-writes (independent) cover part of latency
    ushort8 vreg[4];
    #pragma unroll
    for (int i = 0; i < 4; i++){
      const int id = t + 256*i;
      vreg[i] = *(const ushort8*)(vb + (size_t)(id>>2)*NSP + key0 + (id&3)*8);
    }
    #pragma unroll
    for (int i = 0; i < 4; i++){
      const int id = t + 256*i;
      *(ushort8*)&Kt[(id>>5)*260 + (id&31)*8] = kreg[i];
    }
    #pragma unroll
    for (int i = 0; i < 4; i++){
      const int id = t + 256*i;
      *(ushort8*)&Vt[(id>>2)*36 + (id&3)*8] = vreg[i];
    }
    __syncthreads();                       // staged

    // prefetch next K tile -> regs; latency hidden behind compute below
    if (it + 1 < iters){
      const int nk0 = key0 + 32;
      #pragma unroll
      for (int i = 0; i < 4; i++){
        const int id = t + 256*i;
        kreg[i] = *(const ushort8*)(kb + (size_t)(nk0 + (id>>5))*CCH + (id&31)*8);
      }
    }

    // S^T = K * Q^T : A = K (row=cl=key, k=ch h*8+j), B = Q (regs)
    f32x16 sacc = (f32x16)(0.f);
    #pragma unroll
    for (int st = 0; st < 16; st++){
      short8 kf = *(const short8*)&Kt[cl*260 + st*16 + h*8];
      sacc = __builtin_amdgcn_mfma_f32_32x32x16_bf16(kf, qf[st], sacc, 0, 0, 0);
    }

    // fixed-M softmax; C/D: lane holds q=cl, key(reg r) = (r&3)+8*(r>>2)+4h
    unsigned int grp[4][2];
    #pragma unroll
    for (int m = 0; m < 4; m++){
      float p0 = __builtin_amdgcn_exp2f(fminf(sacc[4*m+0]*c1 - M2, 30.f));
      float p1 = __builtin_amdgcn_exp2f(fminf(sacc[4*m+1]*c1 - M2, 30.f));
      float p2 = __builtin_amdgcn_exp2f(fminf(sacc[4*m+2]*c1 - M2, 30.f));
      float p3 = __builtin_amdgcn_exp2f(fminf(sacc[4*m+3]*c1 - M2, 30.f));
      l_i += (p0 + p1) + (p2 + p3);
      grp[m][0] = pk2(p0, p1);
      grp[m][1] = pk2(p2, p3);
    }
    // half-exchange: build P A-frags (lane q=cl, k-chunk h*8+j per 16-key step)
    unsigned int sa0 = h ? grp[0][0] : grp[1][0];
    unsigned int sa1 = h ? grp[0][1] : grp[1][1];
    unsigned int sb0 = h ? grp[2][0] : grp[3][0];
    unsigned int sb1 = h ? grp[2][1] : grp[3][1];
    unsigned int ra0 = __shfl_xor((int)sa0, 32, 64);
    unsigned int ra1 = __shfl_xor((int)sa1, 32, 64);
    unsigned int rb0 = __shfl_xor((int)sb0, 32, 64);
    unsigned int rb1 = __shfl_xor((int)sb1, 32, 64);
    unsigned int f0[4], f1[4];
    if (h == 0){
      f0[0]=grp[0][0]; f0[1]=grp[0][1]; f0[2]=ra0; f0[3]=ra1;
      f1[0]=grp[2][0]; f1[1]=grp[2][1]; f1[2]=rb0; f1[3]=rb1;
    } else {
      f0[0]=ra0; f0[1]=ra1; f0[2]=grp[1][0]; f0[3]=grp[1][1];
      f1[0]=rb0; f1[1]=rb1; f1[2]=grp[3][0]; f1[3]=grp[3][1];
    }
    short8 pf0, pf1;
    __builtin_memcpy(&pf0, f0, 16);
    __builtin_memcpy(&pf1, f1, 16);

    // O[q][c] += P * V : B = V (lane c=ct*32+cl, keys st*16 + h*8 + j)
    #pragma unroll
    for (int ct = 0; ct < 8; ct++){
      short8 v0 = *(const short8*)&Vt[(ct*32 + cl)*36 + h*8];
      short8 v1 = *(const short8*)&Vt[(ct*32 + cl)*36 + 16 + h*8];
      oacc[ct] = __builtin_amdgcn_mfma_f32_32x32x16_bf16(pf0, v0, oacc[ct], 0, 0, 0);
      oacc[ct] = __builtin_amdgcn_mfma_f32_32x32x16_bf16(pf1, v1, oacc[ct], 0, 0, 0);
    }
  }

  // partial store: PhT[s][b][c][q] (lane holds col c = ct*32+cl, 16 q rows)
  ushort* ps = (s < 2) ? (ph01 + (size_t)s*TEN) : (ph23 + (size_t)(s-2)*TEN);
  ps += (size_t)b * NSP * CCH;
  #pragma unroll
  for (int ct = 0; ct < 8; ct++){
    const size_t crow = (size_t)(ct*32 + cl) * NSP;
    #pragma unroll
    for (int m = 0; m < 4; m++){
      unsigned int d0 = pk2(oacc[ct][4*m+0], oacc[ct][4*m+1]);
      unsigned int d1 = pk2(oacc[ct][4*m+2], oacc[ct][4*m+3]);
      uint2 dv; dv.x = d0; dv.y = d1;
      *(uint2*)(ps + crow + qb + 8*m + 4*h) = dv;
    }
  }
  l_i += __shfl_xor(l_i, 32, 64);
  if (h == 0)
    lbuf[(size_t)s*BB*NSP + (size_t)b*NSP + qb + cl] = l_i;
}

// ---------------- combine: sum ks partials, normalize, transpose to Oc[q][c] ---
__global__ __launch_bounds__(256) void combine_k(const ushort* __restrict__ ph01,
                                                 const ushort* __restrict__ ph23,
                                                 const float* __restrict__ lbuf,
                                                 ushort* __restrict__ Oc, int ks){
  __shared__ ushort T[64*66];
  const int t = threadIdx.x;
  const int q0 = blockIdx.x * 64, c0 = blockIdx.y * 64, b = blockIdx.z;
  const int ql = t & 63, cs = t >> 6;
  float suml = 0.f;
  for (int sp = 0; sp < ks; sp++) suml += lbuf[(size_t)sp*BB*NSP + (size_t)b*NSP + q0 + ql];
  const float rl = 1.f / suml;
  #pragma unroll
  for (int ci = 0; ci < 16; ci++){
    const int c = cs*16 + ci;
    float acc = 0.f;
    for (int sp = 0; sp < ks; sp++){
      const ushort* pp = (sp < 2) ? (ph01 + (size_t)sp*TEN) : (ph23 + (size_t)(sp-2)*TEN);
      acc += b2f(pp[((size_t)b*CCH + c0 + c)*NSP + q0 + ql]);
    }
    T[ql*66 + c] = f2b(acc * rl);
  }
  __syncthreads();
  const int q2 = t >> 2, ch = (t & 3) * 16;
  ushort8 o0, o1;
  #pragma unroll
  for (int j = 0; j < 8; j++){ o0[j] = T[q2*66 + ch + j]; o1[j] = T[q2*66 + ch + 8 + j]; }
  ushort* dst = Oc + ((size_t)b*NSP + q0 + q2)*CCH + c0 + ch;
  *(ushort8*)dst = o0;
  *(ushort8*)(dst + 8) = o1;
}

// ---------------- final projection + bias + residual (f32 out) -----------------
__global__ __launch_bounds__(256) void gemm_proj_k(const ushort* __restrict__ A,
                                                   const ushort* __restrict__ Bm,
                                                   const float* __restrict__ b3,
                                                   const float* __restrict__ xin,
                                                   float* __restrict__ out){
  __shared__ ushort Bt[64*256];
  const int K = 256;
  const int t = threadIdx.x, w = t >> 6, lane = t & 63;
  const int li = lane & 15, quad = lane >> 4;
  const int tm = blockIdx.x & 63, tn = blockIdx.x >> 6;
  const int batch = blockIdx.y;
  A   += (size_t)batch * NSP * CCH;
  xin += (size_t)batch * CCH * NSP;
  out += (size_t)batch * CCH * NSP;
  const int m0 = tm*64 + w*16;
  const int nb = tn*64;

  #pragma unroll
  for (int i = 0; i < 8; i++){
    const int id = t + 256*i;
    const int row = id >> 5, gg = id & 31;
    *(ushort8*)&Bt[row*256 + (gg ^ (row & 31))*8] =
      *(const ushort8*)(Bm + (size_t)(nb + row)*K + gg*8);
  }
  short8 afr[8];
  #pragma unroll
  for (int kk = 0; kk < 8; kk++)
    afr[kk] = *(const short8*)(A + (size_t)(m0 + li)*K + kk*32 + quad*8);
  __syncthreads();

  #pragma unroll
  for (int nt = 0; nt < 4; nt++){
    f32x4 acc = {0.f,0.f,0.f,0.f};
    const int d = nb + nt*16 + li;
    const int rowl = nt*16 + li;
    #pragma unroll
    for (int kk = 0; kk < 8; kk++){
      short8 bfr = *(const short8*)&Bt[rowl*256 + ((4*kk + quad) ^ (rowl & 31))*8];
      acc = __builtin_amdgcn_mfma_f32_16x16x32_bf16(afr[kk], bfr, acc, 0, 0, 0);
    }
    const float bias = b3[d];
    const size_t idx = (size_t)d*NSP + m0 + quad*4;
    f32x4 xv = *(const f32x4*)(xin + idx);
    f32x4 ov;
    #pragma unroll
    for (int r = 0; r < 4; r++) ov[r] = acc[r] + bias + xv[r];
    *(f32x4*)(out + idx) = ov;
  }
}

extern "C" void kernel_launch(void* const* d_in, const int* in_sizes, int n_in,
                              void* d_out, int out_size, void* d_ws, size_t ws_size,
                              hipStream_t stream){
  const float* x     = (const float*)d_in[0];
  const float* gamma = (const float*)d_in[1];
  const float* beta  = (const float*)d_in[2];
  const float* w0    = (const float*)d_in[3];
  const float* b0    = (const float*)d_in[4];
  const float* w1    = (const float*)d_in[5];
  const float* b1    = (const float*)d_in[6];
  const float* w2    = (const float*)d_in[7];
  const float* b2    = (const float*)d_in[8];
  const float* w3    = (const float*)d_in[9];
  const float* b3    = (const float*)d_in[10];
  float* out = (float*)d_out;

  ushort* h_t  = (ushort*)d_out;                  // d_out scratch (dead later)
  ushort* ph01 = (ushort*)d_out;                  // partial splits 0,1 (16 MB)
  ushort* q_t = (ushort*)d_ws;
  ushort* k_t = q_t + TEN;                        // later reused as Oc
  ushort* v   = k_t + TEN;
  ushort* wT  = v + TEN;                          // 4 x 65536 bf16
  float* stats = (float*)(wT + 4*65536);
  float* lbuf  = stats + 256;                     // up to 4*16384 f32
  ushort* ph23 = (ushort*)(lbuf + 4*BB*NSP);      // partial splits 2,3 (16 MB)

  const size_t need4 = ((3*TEN + 4*65536)*2) + (256 + 4*BB*NSP)*4 + 2*TEN*2;
  const int ks = (ws_size >= need4) ? 4 : 2;
  const int iters = NSP / (ks * 32);

  transpose_w4_k<<<dim3(16,4), 256, 0, stream>>>(w0, w1, w2, w3, wT);
  gn_stats_k<<<128, 256, 0, stream>>>(x, stats);
  gn_apply_k<<<dim3(64,4,4), 256, 0, stream>>>(x, stats, gamma, beta, h_t);

  const long HS = (long)NSP * CCH;
  gemm_lds_k<<<dim3(256, BB), 256, 0, stream>>>(wT,         h_t, q_t, 256, 4096, 0, HS, HS, b0, nullptr);
  gemm_lds_k<<<dim3(256, BB), 256, 0, stream>>>(wT+65536,   h_t, k_t, 256, 4096, 0, HS, HS, b1, nullptr);
  gemm_lds_k<<<dim3(256, BB), 256, 0, stream>>>(h_t, wT+2*65536, v, 4096, 256, HS, 0, HS, nullptr, b2);

  attn32_k<<<128*ks, 256, 0, stream>>>(q_t, k_t, v, ph01, ph23, lbuf, iters, 4*ks);

  ushort* Oc = k_t;                               // k_t dead after attn
  combine_k<<<dim3(64, 4, BB), 256, 0, stream>>>(ph01, ph23, lbuf, Oc, ks);
  gemm_proj_k<<<dim3(256, BB), 256, 0, stream>>>(Oc, wT + 3*65536, b3, x, out);
}